// Round 20
// baseline (114.092 us; speedup 1.0000x reference)
//
#include <hip/hip_runtime.h>
#include <math.h>

#pragma clang fp contract(off)

// Problem constants
#define B_   128
#define CI_  16
#define CO_  32
#define H_   32
#define W_   32
#define HO_  30
#define WO_  30
#define P_   900                 // HO*WO
#define CP_  (CO_*P_)            // 28800
#define N_   ((size_t)B_*CP_)    // 3686400 elements per tensor
#define NBLK_CONV (4*30*8)       // stat slots = 960 (UNCHANGED -> stats bitwise identical)
#define WSTRIDE_O 129600         // CI_*P_*9
#define WSTRIDE_C 8100           // P_*9
#define FFC_ (H_*W_)             // 1024  (channel stride in ff)
#define FFB_ (CI_*H_*W_)         // 16384 (batch stride in ff)
#define FFTOT_ (B_*FFB_)         // 2097152 total ff floats

// d_out layout (4*N_ floats): [0,N)=soma, [N,2N)=spike, [2N,3N)=a_new, [3N,4N)=b_new.
// Slot [3N,4N) temporarily holds the f32 conv value; LIF reads it before
// overwriting with b_new.

// async global->LDS. LDS dest is wave-uniform base + lane*width.
typedef __attribute__((address_space(1))) const unsigned int gas_uint;
typedef __attribute__((address_space(3))) unsigned int las_uint;
__device__ __forceinline__ void gload_lds4(const float* g, float* l) {
    __builtin_amdgcn_global_load_lds((gas_uint*)g, (las_uint*)l, 4, 0, 0);
}
__device__ __forceinline__ void gload_lds16(const float* g, float* l) {
    __builtin_amdgcn_global_load_lds((gas_uint*)g, (las_uint*)l, 16, 0, 0);
}

// ---------------------------------------------------------------------------
// Kernel 1: locally-connected conv. R19 VERBATIM (champion component:
// FETCH 45MB, ~65us rocprof). Body = R17 (64 thr = 8o x 8w x 16b, thread =
// 2o x 2w x 4b; weight LDS 8x76 + k8 plane, w*8+k layout matches staging;
// o-interleave kills wk bank conflicts). Grid 3840 1-D with XCD/temporal
// remap: id = g3*256 + m*8 + gl; G = g3*8+gl = (wt,h) group; all 32 sharers
// (8 z x 4 os) = gl (mod 8) -> same XCD within a 256-id span (working set
// 443KB << 4MB L2). Stats: same 960x32 f64 slots -> BITWISE identical.
// NOTE (R4/R6/R18 lessons): no VGPR cap, no pointer rotation, no barrier-
// free counted-vmcnt, 2-deep only.
// ---------------------------------------------------------------------------
__global__ __launch_bounds__(64) void conv_kernel(
    const float* __restrict__ ff, const float* __restrict__ weight,
    const float* __restrict__ conv_bias, float* __restrict__ outf,
    double* __restrict__ part_sum, double* __restrict__ part_sumsq)
{
#pragma clang fp contract(off)
    const int tid = threadIdx.x;        // 0..63
    const int og  = tid & 3;            // 0..3
    const int wg2 = (tid >> 2) & 3;     // 0..3
    const int bg  = (tid >> 4) & 3;     // 0..3
    // ---- XCD/temporal remap decode ----
    const int D   = blockIdx.x;         // 0..3839
    const int gl  = D & 7;
    const int rr  = D >> 3;
    const int m   = rr & 31;            // 0..31
    const int g3  = rr >> 5;            // 0..14
    const int G   = g3 * 8 + gl;        // 0..119 (wt,h) group
    const int wt  = G & 3;              // 0..3
    const int h   = G >> 2;             // 0..29
    const int os  = m & 3;              // 0..3  (8-o slice)
    const int zb  = m >> 2;             // 0..7
    const int b0  = zb * 16;            // 16 batches per block
    const int w0  = wt * 8 + wg2 * 2;
    const bool val = !(wt == 3 && wg2 == 3);
    const int ob  = os * 8;             // global o base

    __shared__ float wgl[2][672];       // 8x76 (608) + k8 plane 608..671
    __shared__ float ffs[2][576];       // [bb*36 + r*12 + cc]

    // ---- c-independent staging offsets (all in-bounds by construction) ----
    int wq_off[11];
#pragma unroll
    for (int q = 0; q < 11; ++q) {
        int mm = q * 64 + tid;          // q=10 masked to tid<32 at issue
        int src = 0;
        if (mm < 608) {
            int ol = mm / 76, r = mm - ol * 76;
            if (r < 64) {                       // DATA: layout w*8+k (matches compute)
                int w = r >> 3, k = r & 7;
                int colc = wt * 8 + w; if (colc > 29) colc = 29;   // edge clamp
                src = (ob + ol) * WSTRIDE_O + (h * WO_ + colc) * 9 + k;
            }
        } else if (mm < 672) {
            int idx = mm - 608, ol = idx >> 3, w = idx & 7;
            int colc = wt * 8 + w; if (colc > 29) colc = 29;
            src = (ob + ol) * WSTRIDE_O + (h * WO_ + colc) * 9 + 8;
        }
        wq_off[q] = src;
    }
    int f_off[3];
#pragma unroll
    for (int q = 0; q < 3; ++q) {
        int d = q * 256 + tid * 4;
        int dd = (d < 576) ? d : 0;
        int bb = dd / 36, rm = dd - bb * 36, r = rm / 12, cc0 = rm - r * 12;
        f_off[q] = (b0 + bb) * FFB_ + (h + r) * W_ + wt * 8 + cc0;  // 16B-aligned
    }

    float acc[2][2][4];                  // [oo][ww][j]
#pragma unroll
    for (int oo = 0; oo < 2; ++oo)
#pragma unroll
        for (int ww = 0; ww < 2; ++ww)
#pragma unroll
            for (int j = 0; j < 4; ++j) acc[oo][ww][j] = 0.f;

    auto stage = [&](int c, int buf) {
        const float* wsrc = weight + c * WSTRIDE_C;
#pragma unroll
        for (int q = 0; q < 10; ++q)
            gload_lds4(wsrc + wq_off[q], &wgl[buf][q * 64]);
        if (tid < 32)
            gload_lds4(wsrc + wq_off[10], &wgl[buf][640]);
#pragma unroll
        for (int q = 0; q < 3; ++q) {
            if (q < 2 || tid < 16) {
                int g = f_off[q] + c * FFC_;
                if (g > FFTOT_ - 4) g = FFTOT_ - 4;  // corner clamp (garbage slots only)
                gload_lds16(ff + g, &ffs[buf][q * 256]);
            }
        }
    };

    auto compute_c = [&](int buf) {
        float wk[2][2][9];
#pragma unroll
        for (int oo = 0; oo < 2; ++oo)
#pragma unroll
            for (int ww = 0; ww < 2; ++ww) {
                const int ol = oo * 4 + og, w = wg2 * 2 + ww;     // o-interleave
                const float* wp = &wgl[buf][ol * 76 + w * 8];     // 304B stride, 16B-aligned
                const float4 a = *reinterpret_cast<const float4*>(wp);
                const float4 b = *reinterpret_cast<const float4*>(wp + 4);
                wk[oo][ww][0] = a.x; wk[oo][ww][1] = a.y; wk[oo][ww][2] = a.z; wk[oo][ww][3] = a.w;
                wk[oo][ww][4] = b.x; wk[oo][ww][5] = b.y; wk[oo][ww][6] = b.z; wk[oo][ww][7] = b.w;
                wk[oo][ww][8] = wgl[buf][608 + ol * 8 + w];
            }
#pragma unroll
        for (int j = 0; j < 4; ++j) {
            const int bb = bg * 4 + j;
            float fr[3][4];
#pragma unroll
            for (int r = 0; r < 3; ++r) {
                const float2 u = *reinterpret_cast<const float2*>(&ffs[buf][bb * 36 + r * 12 + wg2 * 2]);
                const float2 v = *reinterpret_cast<const float2*>(&ffs[buf][bb * 36 + r * 12 + wg2 * 2 + 2]);
                fr[r][0] = u.x; fr[r][1] = u.y; fr[r][2] = v.x; fr[r][3] = v.y;
            }
#pragma unroll
            for (int oo = 0; oo < 2; ++oo)
#pragma unroll
                for (int ww = 0; ww < 2; ++ww) {
                    float a = acc[oo][ww][j];
#pragma unroll
                    for (int kh = 0; kh < 3; ++kh)
#pragma unroll
                        for (int kw = 0; kw < 3; ++kw) {
                            float prod = wk[oo][ww][kh * 3 + kw] * fr[kh][ww + kw];
                            a = a + prod;      // no FMA, (c,kh,kw) order
                        }
                    acc[oo][ww][j] = a;
                }
        }
    };

    stage(0, 0);
    __syncthreads();
    for (int cs = 0; cs < CI_; cs += 2) {
        if (cs + 1 < CI_) stage(cs + 1, 1);   // prefetch overlaps compute
        compute_c(0);
        __syncthreads();
        if (cs + 2 < CI_) stage(cs + 2, 0);
        compute_c(1);
        __syncthreads();
    }

    // epilogue: bias, park conv values, exact f64 per-slot per-channel stats
    double s1[2] = {0.0, 0.0}, s2[2] = {0.0, 0.0};
    if (val) {
#pragma unroll
        for (int oo = 0; oo < 2; ++oo) {
            const int o = ob + oo * 4 + og;
            const int pidx = o * P_ + h * WO_ + w0;
            const float2 bi = *reinterpret_cast<const float2*>(conv_bias + pidx);
#pragma unroll
            for (int j = 0; j < 4; ++j) {
                const int b = b0 + bg * 4 + j;
                const size_t n = (size_t)b * CP_ + (size_t)pidx;
                float v0 = acc[oo][0][j] + bi.x;     // f32, same as ref
                float v1 = acc[oo][1][j] + bi.y;
                *reinterpret_cast<float2*>(outf + 3 * N_ + n) = make_float2(v0, v1);
                double d0 = (double)v0, d1 = (double)v1;
                s1[oo] += d0; s2[oo] += d0 * d0;
                s1[oo] += d1; s2[oo] += d1 * d1;
            }
        }
    }
    // deterministic reduce over the 16 lanes (stride 4) sharing og
#pragma unroll
    for (int d = 4; d < 64; d <<= 1) {
#pragma unroll
        for (int oo = 0; oo < 2; ++oo) {
            s1[oo] += __shfl_xor(s1[oo], d);
            s2[oo] += __shfl_xor(s2[oo], d);
        }
    }
    if ((tid & 60) == 0) {               // wg2==0 && bg==0: tid 0..3
        int blk = (zb * 30 + h) * 4 + wt;            // same 0..959 slots
#pragma unroll
        for (int oo = 0; oo < 2; ++oo) {
            const int o = ob + oo * 4 + og;
            part_sum  [blk * CO_ + o] = s1[oo];
            part_sumsq[blk * CO_ + o] = s2[oo];
        }
    }
}

// ---------------------------------------------------------------------------
// Kernel 2: BN finalize — deterministic f64 reduction of partials (960
// slots), then f32 mean / inv_std per channel. UNCHANGED.
// ---------------------------------------------------------------------------
__global__ __launch_bounds__(256) void bn_finalize(
    const double* __restrict__ part_sum, const double* __restrict__ part_sumsq,
    float* __restrict__ Mb)
{
#pragma clang fp contract(off)
    const int o = blockIdx.x;
    const int tid = threadIdx.x;
    double s1 = 0.0, s2 = 0.0;
    for (int i = tid; i < NBLK_CONV; i += 256) {
        s1 += part_sum[i * CO_ + o];
        s2 += part_sumsq[i * CO_ + o];
    }
    __shared__ double r1[256], r2[256];
    r1[tid] = s1; r2[tid] = s2;
    __syncthreads();
    for (int s = 128; s > 0; s >>= 1) {
        if (tid < s) { r1[tid] += r1[tid + s]; r2[tid] += r2[tid + s]; }
        __syncthreads();
    }
    if (tid == 0) {
        const double cnt = (double)(B_ * (size_t)P_);
        double mean = r1[0] / cnt;
        float meanf = (float)mean;
        double md = (double)meanf;
        double var = r2[0] / cnt - 2.0 * md * (r1[0] / cnt) + md * md;
        float varf = (float)var;
        float invf = 1.0f / sqrtf(varf + 1e-5f);
        Mb[o]       = meanf;
        Mb[CO_ + o] = invf;
    }
}

// ---------------------------------------------------------------------------
// Kernel 3: fused recurrent-bmm + LIF. R15's round structure (4 rounds x
// 2 batches, register prefetch, lgkmcnt(0)-only barrier) in the UNTESTED
// 512-thread geometry: 32 i x 16 p. Mechanics vs the 1024-thr champion:
// ~3.6 blocks/CU (was 1.8) -> 2x independent barrier groups per CU; 8-wave
// convoys (was 16); 16-p runs = 64 B = full sector (R9's 8-p halved that
// and doubled FETCH); LDS 8 KB, VGPR ~44. XCD decode: D&7 = pt8, the 16
// bg-sharers of a local_rec/tau/spk p-slice land on one XCD. Grid 1024 =
// 8 ptq x 16 bg x 8 pt8; pt = ptq*8+pt8; 57 active p-tiles.
// Math/order identical -> bit-identical outputs.
// ---------------------------------------------------------------------------
__global__ __launch_bounds__(512) void lif_rec_kernel(
    float* __restrict__ outf, const float* __restrict__ local_rec,
    const float* __restrict__ tau_m, const float* __restrict__ tau_adp,
    const float* __restrict__ tau_a, const float* __restrict__ Mb,
    const float* __restrict__ gamma, const float* __restrict__ beta,
    const float* __restrict__ fb, const float* __restrict__ soma_t,
    const float* __restrict__ spk_t, const float* __restrict__ a_curr,
    const float* __restrict__ b_t)
{
#pragma clang fp contract(off)
    const int D    = blockIdx.x;         // 0..1023
    const int pt8  = D & 7;
    const int rest = D >> 3;
    const int bg   = rest & 15;
    const int ptq  = rest >> 4;          // 0..7
    const int pt   = ptq * 8 + pt8;      // 0..63
    if (pt >= 57) return;                // 57 p-tiles of 16 cover P_=900

    const int tid = threadIdx.x;
    const int pp  = tid & 15;
    const int i   = tid >> 4;            // channel 0..31
    const int p   = pt * 16 + pp;
    const bool pv = (p < P_);
    const int b0  = bg * 8;

    float L[32];
    float meanf = 0.f, invf = 0.f, gm = 0.f, be = 0.f;
    float al = 0.f, rh = 0.f, et = 0.f;
    int rem = 0;
    if (pv) {
        const float4* lp = reinterpret_cast<const float4*>(local_rec + (size_t)p * (CO_ * CO_) + i * CO_);
#pragma unroll
        for (int q = 0; q < 8; ++q) {
            float4 v = lp[q];
            L[4 * q] = v.x; L[4 * q + 1] = v.y; L[4 * q + 2] = v.z; L[4 * q + 3] = v.w;
        }
        rem = i * P_ + p;
        meanf = Mb[i]; invf = Mb[CO_ + i];
        gm = gamma[i]; be = beta[i];
        // identical f32 ops to the original tau table: f32 divide then f32 exp
        al = expf(-0.5f / tau_m[rem]);
        rh = expf(-0.5f / tau_adp[rem]);
        et = expf(-0.5f / tau_a[rem]);
    }
    const float omr = 1.0f - rh;

    __shared__ float sp[4][CO_][16];     // 8 KB: two double-buffered tile PAIRS

    // prologue: operands for batches b0, b0+1
    size_t n = (size_t)b0 * CP_ + (size_t)rem;
    float sk0 = 0.f, cv0 = 0.f, bt0 = 0.f, ac0 = 0.f, fb0 = 0.f, so0 = 0.f;
    float sk1 = 0.f, cv1 = 0.f, bt1 = 0.f, ac1 = 0.f, fb1 = 0.f, so1 = 0.f;
    if (pv) {
        sk0 = spk_t[n];       cv0 = outf[3 * N_ + n];       bt0 = b_t[n];
        ac0 = a_curr[n];      fb0 = fb[n];                  so0 = soma_t[n];
        const size_t n1 = n + (size_t)CP_;
        sk1 = spk_t[n1];      cv1 = outf[3 * N_ + n1];      bt1 = b_t[n1];
        ac1 = a_curr[n1];     fb1 = fb[n1];                 so1 = soma_t[n1];
    }

#pragma unroll
    for (int r = 0; r < 4; ++r) {
        const int t0 = (r & 1) * 2;      // literal after unroll
        if (pv) {
            sp[t0][i][pp]     = sk0;
            sp[t0 + 1][i][pp] = sk1;
        }
        // prefetch operands for batches 2r+2, 2r+3 BEFORE the barrier
        // (vmcnt ops stay in flight: the raw barrier drains lgkmcnt only)
        float sk0n = 0.f, cv0n = 0.f, bt0n = 0.f, ac0n = 0.f, fb0n = 0.f, so0n = 0.f;
        float sk1n = 0.f, cv1n = 0.f, bt1n = 0.f, ac1n = 0.f, fb1n = 0.f, so1n = 0.f;
        if (r < 3 && pv) {
            const size_t n2 = n + (size_t)(2 * CP_);
            const size_t n3 = n + (size_t)(3 * CP_);
            sk0n = spk_t[n2];  cv0n = outf[3 * N_ + n2];  bt0n = b_t[n2];
            ac0n = a_curr[n2]; fb0n = fb[n2];             so0n = soma_t[n2];
            sk1n = spk_t[n3];  cv1n = outf[3 * N_ + n3];  bt1n = b_t[n3];
            ac1n = a_curr[n3]; fb1n = fb[n3];             so1n = soma_t[n3];
        }
        asm volatile("s_waitcnt lgkmcnt(0)\n\ts_barrier" ::: "memory");
        if (pv) {
            // ---- batch 2r ----
            {
                float rec = 0.f;
#pragma unroll
                for (int j = 0; j < CO_; ++j) {
                    float prod = L[j] * sp[t0][j][pp];
                    rec = rec + prod;
                }
                float t  = cv0 - meanf;
                float x  = t * invf;
                float xg = x * gm;
                float cx = xg + be;
                cx = cx + rec;
                float rb  = rh * bt0;
                float os  = omr * sk0;
                float bn  = rb + os;
                float tb = 1.8f * bn;
                float th = 0.1f + tb;
                float ea = et * ac0;
                float an = ea + fb0;
                float sg = 1.0f / (1.0f + expf(-an));
                float as = al * so0;
                float s5 = sg - 0.5f;
                float u1 = as + s5;
                float u2 = u1 + cx;
                float ts = th * sk0;
                float sn = u2 - ts;
                outf[n]          = sn;
                outf[N_ + n]     = ((sn - th) > 0.0f) ? 1.f : 0.f;
                outf[2 * N_ + n] = an;
                outf[3 * N_ + n] = bn;
            }
            // ---- batch 2r+1 ----
            {
                const size_t n1 = n + (size_t)CP_;
                float rec = 0.f;
#pragma unroll
                for (int j = 0; j < CO_; ++j) {
                    float prod = L[j] * sp[t0 + 1][j][pp];
                    rec = rec + prod;
                }
                float t  = cv1 - meanf;
                float x  = t * invf;
                float xg = x * gm;
                float cx = xg + be;
                cx = cx + rec;
                float rb  = rh * bt1;
                float os  = omr * sk1;
                float bn  = rb + os;
                float tb = 1.8f * bn;
                float th = 0.1f + tb;
                float ea = et * ac1;
                float an = ea + fb1;
                float sg = 1.0f / (1.0f + expf(-an));
                float as = al * so1;
                float s5 = sg - 0.5f;
                float u1 = as + s5;
                float u2 = u1 + cx;
                float ts = th * sk1;
                float sn = u2 - ts;
                outf[n1]          = sn;
                outf[N_ + n1]     = ((sn - th) > 0.0f) ? 1.f : 0.f;
                outf[2 * N_ + n1] = an;
                outf[3 * N_ + n1] = bn;
            }
        }
        sk0 = sk0n; cv0 = cv0n; bt0 = bt0n; ac0 = ac0n; fb0 = fb0n; so0 = so0n;
        sk1 = sk1n; cv1 = cv1n; bt1 = bt1n; ac1 = ac1n; fb1 = fb1n; so1 = so1n;
        n += (size_t)(2 * CP_);
    }
}

extern "C" void kernel_launch(void* const* d_in, const int* in_sizes, int n_in,
                              void* d_out, int out_size, void* d_ws, size_t ws_size,
                              hipStream_t stream)
{
    const float* ff        = (const float*)d_in[0];
    const float* fb        = (const float*)d_in[1];
    const float* soma_t    = (const float*)d_in[2];
    const float* spk_t     = (const float*)d_in[3];
    const float* a_curr    = (const float*)d_in[4];
    const float* b_t       = (const float*)d_in[5];
    const float* weight    = (const float*)d_in[6];
    const float* conv_bias = (const float*)d_in[7];
    const float* local_rec = (const float*)d_in[8];
    const float* gamma     = (const float*)d_in[9];
    const float* beta      = (const float*)d_in[10];
    const float* tau_m     = (const float*)d_in[11];
    const float* tau_adp   = (const float*)d_in[12];
    const float* tau_a     = (const float*)d_in[13];

    // ws: f64 partials then Mb (~0.5 MB total)
    double* part_sum = (double*)d_ws;                       // NBLK_CONV*CO_
    double* part_sq  = part_sum + (size_t)NBLK_CONV * CO_;  // NBLK_CONV*CO_
    float*  Mb       = (float*)(part_sq + (size_t)NBLK_CONV * CO_);  // 64

    float* outf = (float*)d_out;

    conv_kernel<<<dim3(3840), 64, 0, stream>>>(
        ff, weight, conv_bias, outf, part_sum, part_sq);
    bn_finalize<<<dim3(CO_), 256, 0, stream>>>(part_sum, part_sq, Mb);
    lif_rec_kernel<<<dim3(1024), 512, 0, stream>>>(
        outf, local_rec, tau_m, tau_adp, tau_a, Mb, gamma, beta,
        fb, soma_t, spk_t, a_curr, b_t);
}

// Round 21
// 102.103 us; speedup vs baseline: 1.1174x; 1.1174x over previous
//
#include <hip/hip_runtime.h>
#include <math.h>

#pragma clang fp contract(off)

// Problem constants
#define B_   128
#define CI_  16
#define CO_  32
#define H_   32
#define W_   32
#define HO_  30
#define WO_  30
#define P_   900                 // HO*WO
#define CP_  (CO_*P_)            // 28800
#define N_   ((size_t)B_*CP_)    // 3686400 elements per tensor
#define NBLK_CONV (4*30*8)       // stat slots = 960
#define WSTRIDE_O 129600         // CI_*P_*9
#define WSTRIDE_C 8100           // P_*9
#define FFC_ (H_*W_)             // 1024  (channel stride in ff)
#define FFB_ (CI_*H_*W_)         // 16384 (batch stride in ff)
#define FFTOT_ (B_*FFB_)         // 2097152 total ff floats

// d_out layout (4*N_ floats): [0,N)=soma, [N,2N)=spike, [2N,3N)=a_new, [3N,4N)=b_new.
// Slot [3N,4N) temporarily holds the f32 conv value; LIF reads it before
// overwriting with b_new.

// async global->LDS. LDS dest is wave-uniform base + lane*width.
typedef __attribute__((address_space(1))) const unsigned int gas_uint;
typedef __attribute__((address_space(3))) unsigned int las_uint;
__device__ __forceinline__ void gload_lds4(const float* g, float* l) {
    __builtin_amdgcn_global_load_lds((gas_uint*)g, (las_uint*)l, 4, 0, 0);
}
__device__ __forceinline__ void gload_lds16(const float* g, float* l) {
    __builtin_amdgcn_global_load_lds((gas_uint*)g, (las_uint*)l, 16, 0, 0);
}

// ---------------------------------------------------------------------------
// Kernel 1: locally-connected conv. R19 VERBATIM (session champion conv:
// FETCH 45MB, ~65us rocprof, wall 100.9 total). Body = R17 (64 thr = 8o x
// 8w x 16b, thread = 2o x 2w x 4b; weight LDS 8x76 + k8 plane, w*8+k layout
// matches staging; o-interleave -> wk b128 slots all-8-hit-2x = free).
// Grid 3840 1-D with XCD/temporal remap: id = g3*256 + m*8 + gl;
// G = g3*8+gl = (wt,h) group; all 32 sharers (8 z x 4 os) = gl (mod 8) ->
// same XCD within a 256-id span (working set 443KB << 4MB L2).
// Stats: 960x32 f64 slots, deterministic -> BITWISE identical outputs.
// Session lessons pinned: no VGPR cap (R4), no pointer rotation (R4), no
// barrier-free counted-vmcnt across dbuf (R18: VGPR 136 + FETCH 81MB),
// 2-deep only (R6), staging layout == read layout (R16).
// ---------------------------------------------------------------------------
__global__ __launch_bounds__(64) void conv_kernel(
    const float* __restrict__ ff, const float* __restrict__ weight,
    const float* __restrict__ conv_bias, float* __restrict__ outf,
    double* __restrict__ part_sum, double* __restrict__ part_sumsq)
{
#pragma clang fp contract(off)
    const int tid = threadIdx.x;        // 0..63
    const int og  = tid & 3;            // 0..3
    const int wg2 = (tid >> 2) & 3;     // 0..3
    const int bg  = (tid >> 4) & 3;     // 0..3
    // ---- XCD/temporal remap decode ----
    const int D   = blockIdx.x;         // 0..3839
    const int gl  = D & 7;
    const int rr  = D >> 3;
    const int m   = rr & 31;            // 0..31
    const int g3  = rr >> 5;            // 0..14
    const int G   = g3 * 8 + gl;        // 0..119 (wt,h) group
    const int wt  = G & 3;              // 0..3
    const int h   = G >> 2;             // 0..29
    const int os  = m & 3;              // 0..3  (8-o slice)
    const int zb  = m >> 2;             // 0..7
    const int b0  = zb * 16;            // 16 batches per block
    const int w0  = wt * 8 + wg2 * 2;
    const bool val = !(wt == 3 && wg2 == 3);
    const int ob  = os * 8;             // global o base

    __shared__ float wgl[2][672];       // 8x76 (608) + k8 plane 608..671
    __shared__ float ffs[2][576];       // [bb*36 + r*12 + cc]

    // ---- c-independent staging offsets (all in-bounds by construction) ----
    int wq_off[11];
#pragma unroll
    for (int q = 0; q < 11; ++q) {
        int mm = q * 64 + tid;          // q=10 masked to tid<32 at issue
        int src = 0;
        if (mm < 608) {
            int ol = mm / 76, r = mm - ol * 76;
            if (r < 64) {                       // DATA: layout w*8+k (matches compute)
                int w = r >> 3, k = r & 7;
                int colc = wt * 8 + w; if (colc > 29) colc = 29;   // edge clamp
                src = (ob + ol) * WSTRIDE_O + (h * WO_ + colc) * 9 + k;
            }
        } else if (mm < 672) {
            int idx = mm - 608, ol = idx >> 3, w = idx & 7;
            int colc = wt * 8 + w; if (colc > 29) colc = 29;
            src = (ob + ol) * WSTRIDE_O + (h * WO_ + colc) * 9 + 8;
        }
        wq_off[q] = src;
    }
    int f_off[3];
#pragma unroll
    for (int q = 0; q < 3; ++q) {
        int d = q * 256 + tid * 4;
        int dd = (d < 576) ? d : 0;
        int bb = dd / 36, rm = dd - bb * 36, r = rm / 12, cc0 = rm - r * 12;
        f_off[q] = (b0 + bb) * FFB_ + (h + r) * W_ + wt * 8 + cc0;  // 16B-aligned
    }

    float acc[2][2][4];                  // [oo][ww][j]
#pragma unroll
    for (int oo = 0; oo < 2; ++oo)
#pragma unroll
        for (int ww = 0; ww < 2; ++ww)
#pragma unroll
            for (int j = 0; j < 4; ++j) acc[oo][ww][j] = 0.f;

    auto stage = [&](int c, int buf) {
        const float* wsrc = weight + c * WSTRIDE_C;
#pragma unroll
        for (int q = 0; q < 10; ++q)
            gload_lds4(wsrc + wq_off[q], &wgl[buf][q * 64]);
        if (tid < 32)
            gload_lds4(wsrc + wq_off[10], &wgl[buf][640]);
#pragma unroll
        for (int q = 0; q < 3; ++q) {
            if (q < 2 || tid < 16) {
                int g = f_off[q] + c * FFC_;
                if (g > FFTOT_ - 4) g = FFTOT_ - 4;  // corner clamp (garbage slots only)
                gload_lds16(ff + g, &ffs[buf][q * 256]);
            }
        }
    };

    auto compute_c = [&](int buf) {
        float wk[2][2][9];
#pragma unroll
        for (int oo = 0; oo < 2; ++oo)
#pragma unroll
            for (int ww = 0; ww < 2; ++ww) {
                const int ol = oo * 4 + og, w = wg2 * 2 + ww;     // o-interleave
                const float* wp = &wgl[buf][ol * 76 + w * 8];     // 304B stride, 16B-aligned
                const float4 a = *reinterpret_cast<const float4*>(wp);
                const float4 b = *reinterpret_cast<const float4*>(wp + 4);
                wk[oo][ww][0] = a.x; wk[oo][ww][1] = a.y; wk[oo][ww][2] = a.z; wk[oo][ww][3] = a.w;
                wk[oo][ww][4] = b.x; wk[oo][ww][5] = b.y; wk[oo][ww][6] = b.z; wk[oo][ww][7] = b.w;
                wk[oo][ww][8] = wgl[buf][608 + ol * 8 + w];
            }
#pragma unroll
        for (int j = 0; j < 4; ++j) {
            const int bb = bg * 4 + j;
            float fr[3][4];
#pragma unroll
            for (int r = 0; r < 3; ++r) {
                const float2 u = *reinterpret_cast<const float2*>(&ffs[buf][bb * 36 + r * 12 + wg2 * 2]);
                const float2 v = *reinterpret_cast<const float2*>(&ffs[buf][bb * 36 + r * 12 + wg2 * 2 + 2]);
                fr[r][0] = u.x; fr[r][1] = u.y; fr[r][2] = v.x; fr[r][3] = v.y;
            }
#pragma unroll
            for (int oo = 0; oo < 2; ++oo)
#pragma unroll
                for (int ww = 0; ww < 2; ++ww) {
                    float a = acc[oo][ww][j];
#pragma unroll
                    for (int kh = 0; kh < 3; ++kh)
#pragma unroll
                        for (int kw = 0; kw < 3; ++kw) {
                            float prod = wk[oo][ww][kh * 3 + kw] * fr[kh][ww + kw];
                            a = a + prod;      // no FMA, (c,kh,kw) order
                        }
                    acc[oo][ww][j] = a;
                }
        }
    };

    stage(0, 0);
    __syncthreads();
    for (int cs = 0; cs < CI_; cs += 2) {
        if (cs + 1 < CI_) stage(cs + 1, 1);   // prefetch overlaps compute
        compute_c(0);
        __syncthreads();
        if (cs + 2 < CI_) stage(cs + 2, 0);
        compute_c(1);
        __syncthreads();
    }

    // epilogue: bias, park conv values, exact f64 per-slot per-channel stats
    double s1[2] = {0.0, 0.0}, s2[2] = {0.0, 0.0};
    if (val) {
#pragma unroll
        for (int oo = 0; oo < 2; ++oo) {
            const int o = ob + oo * 4 + og;
            const int pidx = o * P_ + h * WO_ + w0;
            const float2 bi = *reinterpret_cast<const float2*>(conv_bias + pidx);
#pragma unroll
            for (int j = 0; j < 4; ++j) {
                const int b = b0 + bg * 4 + j;
                const size_t n = (size_t)b * CP_ + (size_t)pidx;
                float v0 = acc[oo][0][j] + bi.x;     // f32, same as ref
                float v1 = acc[oo][1][j] + bi.y;
                *reinterpret_cast<float2*>(outf + 3 * N_ + n) = make_float2(v0, v1);
                double d0 = (double)v0, d1 = (double)v1;
                s1[oo] += d0; s2[oo] += d0 * d0;
                s1[oo] += d1; s2[oo] += d1 * d1;
            }
        }
    }
    // deterministic reduce over the 16 lanes (stride 4) sharing og
#pragma unroll
    for (int d = 4; d < 64; d <<= 1) {
#pragma unroll
        for (int oo = 0; oo < 2; ++oo) {
            s1[oo] += __shfl_xor(s1[oo], d);
            s2[oo] += __shfl_xor(s2[oo], d);
        }
    }
    if ((tid & 60) == 0) {               // wg2==0 && bg==0: tid 0..3
        int blk = (zb * 30 + h) * 4 + wt;            // same 0..959 slots
#pragma unroll
        for (int oo = 0; oo < 2; ++oo) {
            const int o = ob + oo * 4 + og;
            part_sum  [blk * CO_ + o] = s1[oo];
            part_sumsq[blk * CO_ + o] = s2[oo];
        }
    }
}

// ---------------------------------------------------------------------------
// Kernel 2: BN finalize — deterministic f64 reduction of partials (960
// slots), then f32 mean / inv_std per channel. UNCHANGED all session.
// ---------------------------------------------------------------------------
__global__ __launch_bounds__(256) void bn_finalize(
    const double* __restrict__ part_sum, const double* __restrict__ part_sumsq,
    float* __restrict__ Mb)
{
#pragma clang fp contract(off)
    const int o = blockIdx.x;
    const int tid = threadIdx.x;
    double s1 = 0.0, s2 = 0.0;
    for (int i = tid; i < NBLK_CONV; i += 256) {
        s1 += part_sum[i * CO_ + o];
        s2 += part_sumsq[i * CO_ + o];
    }
    __shared__ double r1[256], r2[256];
    r1[tid] = s1; r2[tid] = s2;
    __syncthreads();
    for (int s = 128; s > 0; s >>= 1) {
        if (tid < s) { r1[tid] += r1[tid + s]; r2[tid] += r2[tid + s]; }
        __syncthreads();
    }
    if (tid == 0) {
        const double cnt = (double)(B_ * (size_t)P_);
        double mean = r1[0] / cnt;
        float meanf = (float)mean;
        double md = (double)meanf;
        double var = r2[0] / cnt - 2.0 * md * (r1[0] / cnt) + md * md;
        float varf = (float)var;
        float invf = 1.0f / sqrtf(varf + 1e-5f);
        Mb[o]       = meanf;
        Mb[CO_ + o] = invf;
    }
}

// ---------------------------------------------------------------------------
// Kernel 3: fused recurrent-bmm + LIF. R15 VERBATIM (best measured lif:
// ~64us rocprof; FETCH 84MB = algorithmic minimum, so latency-bound, not
// traffic-bound). 2 batches per barrier round, 4 spike tiles (16 KB),
// register prefetch, lgkmcnt(0)-only barrier (prefetch stays in flight);
// 1024 thr = 32 i x 32 p (32-p runs = 128B coalescing; R9/R20 proved
// narrower p inflates FETCH); XCD-grouped grid 512 (pt8 = D&7: the 16
// b-sharers of a local_rec/tau/spk p-slice on one XCD's L2).
// ---------------------------------------------------------------------------
__global__ __launch_bounds__(1024) void lif_rec_kernel(
    float* __restrict__ outf, const float* __restrict__ local_rec,
    const float* __restrict__ tau_m, const float* __restrict__ tau_adp,
    const float* __restrict__ tau_a, const float* __restrict__ Mb,
    const float* __restrict__ gamma, const float* __restrict__ beta,
    const float* __restrict__ fb, const float* __restrict__ soma_t,
    const float* __restrict__ spk_t, const float* __restrict__ a_curr,
    const float* __restrict__ b_t)
{
#pragma clang fp contract(off)
    const int D    = blockIdx.x;
    const int pt8  = D & 7;
    const int rest = D >> 3;
    const int by   = rest & 15;
    const int ptq  = rest >> 4;          // 0..3
    const int pt   = ptq * 8 + pt8;      // 0..31
    if (pt >= 29) return;                // 29 p-tiles cover P_=900

    const int tid = threadIdx.x;
    const int pp  = tid & 31;
    const int i   = tid >> 5;            // channel 0..31
    const int p   = pt * 32 + pp;
    const bool pv = (p < P_);
    const int b0  = by * 8;

    float L[32];
    float meanf = 0.f, invf = 0.f, gm = 0.f, be = 0.f;
    float al = 0.f, rh = 0.f, et = 0.f;
    int rem = 0;
    if (pv) {
        const float4* lp = reinterpret_cast<const float4*>(local_rec + (size_t)p * (CO_ * CO_) + i * CO_);
#pragma unroll
        for (int q = 0; q < 8; ++q) {
            float4 v = lp[q];
            L[4 * q] = v.x; L[4 * q + 1] = v.y; L[4 * q + 2] = v.z; L[4 * q + 3] = v.w;
        }
        rem = i * P_ + p;
        meanf = Mb[i]; invf = Mb[CO_ + i];
        gm = gamma[i]; be = beta[i];
        // identical f32 ops to the original tau table: f32 divide then f32 exp
        al = expf(-0.5f / tau_m[rem]);
        rh = expf(-0.5f / tau_adp[rem]);
        et = expf(-0.5f / tau_a[rem]);
    }
    const float omr = 1.0f - rh;

    __shared__ float sp[4][CO_][32];     // 16 KB: two double-buffered tile PAIRS

    // prologue: operands for batches b0, b0+1
    size_t n = (size_t)b0 * CP_ + (size_t)rem;
    float sk0 = 0.f, cv0 = 0.f, bt0 = 0.f, ac0 = 0.f, fb0 = 0.f, so0 = 0.f;
    float sk1 = 0.f, cv1 = 0.f, bt1 = 0.f, ac1 = 0.f, fb1 = 0.f, so1 = 0.f;
    if (pv) {
        sk0 = spk_t[n];       cv0 = outf[3 * N_ + n];       bt0 = b_t[n];
        ac0 = a_curr[n];      fb0 = fb[n];                  so0 = soma_t[n];
        const size_t n1 = n + (size_t)CP_;
        sk1 = spk_t[n1];      cv1 = outf[3 * N_ + n1];      bt1 = b_t[n1];
        ac1 = a_curr[n1];     fb1 = fb[n1];                 so1 = soma_t[n1];
    }

#pragma unroll
    for (int r = 0; r < 4; ++r) {
        const int t0 = (r & 1) * 2;      // literal after unroll
        if (pv) {
            sp[t0][i][pp]     = sk0;
            sp[t0 + 1][i][pp] = sk1;
        }
        // prefetch operands for batches 2r+2, 2r+3 BEFORE the barrier
        // (vmcnt ops stay in flight: the raw barrier drains lgkmcnt only)
        float sk0n = 0.f, cv0n = 0.f, bt0n = 0.f, ac0n = 0.f, fb0n = 0.f, so0n = 0.f;
        float sk1n = 0.f, cv1n = 0.f, bt1n = 0.f, ac1n = 0.f, fb1n = 0.f, so1n = 0.f;
        if (r < 3 && pv) {
            const size_t n2 = n + (size_t)(2 * CP_);
            const size_t n3 = n + (size_t)(3 * CP_);
            sk0n = spk_t[n2];  cv0n = outf[3 * N_ + n2];  bt0n = b_t[n2];
            ac0n = a_curr[n2]; fb0n = fb[n2];             so0n = soma_t[n2];
            sk1n = spk_t[n3];  cv1n = outf[3 * N_ + n3];  bt1n = b_t[n3];
            ac1n = a_curr[n3]; fb1n = fb[n3];             so1n = soma_t[n3];
        }
        asm volatile("s_waitcnt lgkmcnt(0)\n\ts_barrier" ::: "memory");
        if (pv) {
            // ---- batch 2r ----
            {
                float rec = 0.f;
#pragma unroll
                for (int j = 0; j < CO_; ++j) {
                    float prod = L[j] * sp[t0][j][pp];
                    rec = rec + prod;
                }
                float t  = cv0 - meanf;
                float x  = t * invf;
                float xg = x * gm;
                float cx = xg + be;
                cx = cx + rec;
                float rb  = rh * bt0;
                float os  = omr * sk0;
                float bn  = rb + os;
                float tb = 1.8f * bn;
                float th = 0.1f + tb;
                float ea = et * ac0;
                float an = ea + fb0;
                float sg = 1.0f / (1.0f + expf(-an));
                float as = al * so0;
                float s5 = sg - 0.5f;
                float u1 = as + s5;
                float u2 = u1 + cx;
                float ts = th * sk0;
                float sn = u2 - ts;
                outf[n]          = sn;
                outf[N_ + n]     = ((sn - th) > 0.0f) ? 1.f : 0.f;
                outf[2 * N_ + n] = an;
                outf[3 * N_ + n] = bn;
            }
            // ---- batch 2r+1 ----
            {
                const size_t n1 = n + (size_t)CP_;
                float rec = 0.f;
#pragma unroll
                for (int j = 0; j < CO_; ++j) {
                    float prod = L[j] * sp[t0 + 1][j][pp];
                    rec = rec + prod;
                }
                float t  = cv1 - meanf;
                float x  = t * invf;
                float xg = x * gm;
                float cx = xg + be;
                cx = cx + rec;
                float rb  = rh * bt1;
                float os  = omr * sk1;
                float bn  = rb + os;
                float tb = 1.8f * bn;
                float th = 0.1f + tb;
                float ea = et * ac1;
                float an = ea + fb1;
                float sg = 1.0f / (1.0f + expf(-an));
                float as = al * so1;
                float s5 = sg - 0.5f;
                float u1 = as + s5;
                float u2 = u1 + cx;
                float ts = th * sk1;
                float sn = u2 - ts;
                outf[n1]          = sn;
                outf[N_ + n1]     = ((sn - th) > 0.0f) ? 1.f : 0.f;
                outf[2 * N_ + n1] = an;
                outf[3 * N_ + n1] = bn;
            }
        }
        sk0 = sk0n; cv0 = cv0n; bt0 = bt0n; ac0 = ac0n; fb0 = fb0n; so0 = so0n;
        sk1 = sk1n; cv1 = cv1n; bt1 = bt1n; ac1 = ac1n; fb1 = fb1n; so1 = so1n;
        n += (size_t)(2 * CP_);
    }
}

extern "C" void kernel_launch(void* const* d_in, const int* in_sizes, int n_in,
                              void* d_out, int out_size, void* d_ws, size_t ws_size,
                              hipStream_t stream)
{
    const float* ff        = (const float*)d_in[0];
    const float* fb        = (const float*)d_in[1];
    const float* soma_t    = (const float*)d_in[2];
    const float* spk_t     = (const float*)d_in[3];
    const float* a_curr    = (const float*)d_in[4];
    const float* b_t       = (const float*)d_in[5];
    const float* weight    = (const float*)d_in[6];
    const float* conv_bias = (const float*)d_in[7];
    const float* local_rec = (const float*)d_in[8];
    const float* gamma     = (const float*)d_in[9];
    const float* beta      = (const float*)d_in[10];
    const float* tau_m     = (const float*)d_in[11];
    const float* tau_adp   = (const float*)d_in[12];
    const float* tau_a     = (const float*)d_in[13];

    // ws: f64 partials then Mb (~0.5 MB total)
    double* part_sum = (double*)d_ws;                       // NBLK_CONV*CO_
    double* part_sq  = part_sum + (size_t)NBLK_CONV * CO_;  // NBLK_CONV*CO_
    float*  Mb       = (float*)(part_sq + (size_t)NBLK_CONV * CO_);  // 64

    float* outf = (float*)d_out;

    conv_kernel<<<dim3(3840), 64, 0, stream>>>(
        ff, weight, conv_bias, outf, part_sum, part_sq);
    bn_finalize<<<dim3(CO_), 256, 0, stream>>>(part_sum, part_sq, Mb);
    lif_rec_kernel<<<dim3(512), 1024, 0, stream>>>(
        outf, local_rec, tau_m, tau_adp, tau_a, Mb, gamma, beta,
        fb, soma_t, spk_t, a_curr, b_t);
}

// Round 22
// 101.048 us; speedup vs baseline: 1.1291x; 1.0104x over previous
//
#include <hip/hip_runtime.h>
#include <math.h>

#pragma clang fp contract(off)

// Problem constants
#define B_   128
#define CI_  16
#define CO_  32
#define H_   32
#define W_   32
#define HO_  30
#define WO_  30
#define P_   900                 // HO*WO
#define CP_  (CO_*P_)            // 28800
#define N_   ((size_t)B_*CP_)    // 3686400 elements per tensor
#define NBLK_CONV (4*30*8)       // stat slots = 960
#define WSTRIDE_O 129600         // CI_*P_*9
#define WSTRIDE_C 8100           // P_*9
#define FFC_ (H_*W_)             // 1024  (channel stride in ff)
#define FFB_ (CI_*H_*W_)         // 16384 (batch stride in ff)
#define FFTOT_ (B_*FFB_)         // 2097152 total ff floats

// d_out layout (4*N_ floats): [0,N)=soma, [N,2N)=spike, [2N,3N)=a_new, [3N,4N)=b_new.
// Slot [3N,4N) temporarily holds the f32 conv value; LIF reads it before
// overwriting with b_new.

// async global->LDS. LDS dest is wave-uniform base + lane*width.
typedef __attribute__((address_space(1))) const unsigned int gas_uint;
typedef __attribute__((address_space(3))) unsigned int las_uint;
__device__ __forceinline__ void gload_lds4(const float* g, float* l) {
    __builtin_amdgcn_global_load_lds((gas_uint*)g, (las_uint*)l, 4, 0, 0);
}
__device__ __forceinline__ void gload_lds16(const float* g, float* l) {
    __builtin_amdgcn_global_load_lds((gas_uint*)g, (las_uint*)l, 16, 0, 0);
}

// ---------------------------------------------------------------------------
// Kernel 1: locally-connected conv. R19 body VERBATIM; decode changed to
// H-GROUPED XCD remap (write-sector + ff-line sharing fix).
// R21 counter analysis: WRITE_SIZE 26.4MB vs 14.7 min (1.8x) -- each block
// writes 32B (8 w-cols) of every 64B sector; the other half belongs to
// wt+-1, which R19's (wt,h)-grouping placed on a DIFFERENT XCD -> no L2
// write-combining -> 2x write traffic. Likewise one ff row = 32 floats =
// one 128B line shared by ALL 4 wt of an h, split across 4 XCDs.
// Remap: D = ((hq*128+m)<<3)|hl; h = hq*8+hl (grid 4096, h>=30 idle);
// m = zb*16+os*4+wt (wt FASTEST -> wt-quads temporally adjacent). All 128
// blocks of one h on XCD h&7, 8-apart, tight. Working set per h: weights
// 553KB + ff 786KB << 4MB L2. Stat slots (zb*30+h)*4+wt unchanged -> same
// 960 slots, same sums, same butterfly -> BITWISE identical outputs.
// Session lessons pinned: no VGPR cap (R4), no pointer rotation (R4), no
// barrier-free counted-vmcnt across dbuf (R18), 2-deep only (R6),
// staging layout == read layout (R16).
// ---------------------------------------------------------------------------
__global__ __launch_bounds__(64) void conv_kernel(
    const float* __restrict__ ff, const float* __restrict__ weight,
    const float* __restrict__ conv_bias, float* __restrict__ outf,
    double* __restrict__ part_sum, double* __restrict__ part_sumsq)
{
#pragma clang fp contract(off)
    const int tid = threadIdx.x;        // 0..63
    const int og  = tid & 3;            // 0..3
    const int wg2 = (tid >> 2) & 3;     // 0..3
    const int bg  = (tid >> 4) & 3;     // 0..3
    // ---- H-grouped XCD remap decode ----
    const int D   = blockIdx.x;         // 0..4095
    const int hl  = D & 7;
    const int rr  = D >> 3;             // 0..511
    const int m   = rr & 127;           // 0..127
    const int hq  = rr >> 7;            // 0..3
    const int h   = hq * 8 + hl;        // 0..31
    if (h >= HO_) return;               // 256 idle blocks (h = 30, 31)
    const int wt  = m & 3;              // 0..3  (fastest: write-sector sharers adjacent)
    const int os  = (m >> 2) & 3;       // 0..3  (8-o slice)
    const int zb  = m >> 4;             // 0..7
    const int b0  = zb * 16;            // 16 batches per block
    const int w0  = wt * 8 + wg2 * 2;
    const bool val = !(wt == 3 && wg2 == 3);
    const int ob  = os * 8;             // global o base

    __shared__ float wgl[2][672];       // 8x76 (608) + k8 plane 608..671
    __shared__ float ffs[2][576];       // [bb*36 + r*12 + cc]

    // ---- c-independent staging offsets (all in-bounds by construction) ----
    int wq_off[11];
#pragma unroll
    for (int q = 0; q < 11; ++q) {
        int mm = q * 64 + tid;          // q=10 masked to tid<32 at issue
        int src = 0;
        if (mm < 608) {
            int ol = mm / 76, r = mm - ol * 76;
            if (r < 64) {                       // DATA: layout w*8+k (matches compute)
                int w = r >> 3, k = r & 7;
                int colc = wt * 8 + w; if (colc > 29) colc = 29;   // edge clamp
                src = (ob + ol) * WSTRIDE_O + (h * WO_ + colc) * 9 + k;
            }
        } else if (mm < 672) {
            int idx = mm - 608, ol = idx >> 3, w = idx & 7;
            int colc = wt * 8 + w; if (colc > 29) colc = 29;
            src = (ob + ol) * WSTRIDE_O + (h * WO_ + colc) * 9 + 8;
        }
        wq_off[q] = src;
    }
    int f_off[3];
#pragma unroll
    for (int q = 0; q < 3; ++q) {
        int d = q * 256 + tid * 4;
        int dd = (d < 576) ? d : 0;
        int bb = dd / 36, rm = dd - bb * 36, r = rm / 12, cc0 = rm - r * 12;
        f_off[q] = (b0 + bb) * FFB_ + (h + r) * W_ + wt * 8 + cc0;  // 16B-aligned
    }

    float acc[2][2][4];                  // [oo][ww][j]
#pragma unroll
    for (int oo = 0; oo < 2; ++oo)
#pragma unroll
        for (int ww = 0; ww < 2; ++ww)
#pragma unroll
            for (int j = 0; j < 4; ++j) acc[oo][ww][j] = 0.f;

    auto stage = [&](int c, int buf) {
        const float* wsrc = weight + c * WSTRIDE_C;
#pragma unroll
        for (int q = 0; q < 10; ++q)
            gload_lds4(wsrc + wq_off[q], &wgl[buf][q * 64]);
        if (tid < 32)
            gload_lds4(wsrc + wq_off[10], &wgl[buf][640]);
#pragma unroll
        for (int q = 0; q < 3; ++q) {
            if (q < 2 || tid < 16) {
                int g = f_off[q] + c * FFC_;
                if (g > FFTOT_ - 4) g = FFTOT_ - 4;  // corner clamp (garbage slots only)
                gload_lds16(ff + g, &ffs[buf][q * 256]);
            }
        }
    };

    auto compute_c = [&](int buf) {
        float wk[2][2][9];
#pragma unroll
        for (int oo = 0; oo < 2; ++oo)
#pragma unroll
            for (int ww = 0; ww < 2; ++ww) {
                const int ol = oo * 4 + og, w = wg2 * 2 + ww;     // o-interleave
                const float* wp = &wgl[buf][ol * 76 + w * 8];     // 304B stride, 16B-aligned
                const float4 a = *reinterpret_cast<const float4*>(wp);
                const float4 b = *reinterpret_cast<const float4*>(wp + 4);
                wk[oo][ww][0] = a.x; wk[oo][ww][1] = a.y; wk[oo][ww][2] = a.z; wk[oo][ww][3] = a.w;
                wk[oo][ww][4] = b.x; wk[oo][ww][5] = b.y; wk[oo][ww][6] = b.z; wk[oo][ww][7] = b.w;
                wk[oo][ww][8] = wgl[buf][608 + ol * 8 + w];
            }
#pragma unroll
        for (int j = 0; j < 4; ++j) {
            const int bb = bg * 4 + j;
            float fr[3][4];
#pragma unroll
            for (int r = 0; r < 3; ++r) {
                const float2 u = *reinterpret_cast<const float2*>(&ffs[buf][bb * 36 + r * 12 + wg2 * 2]);
                const float2 v = *reinterpret_cast<const float2*>(&ffs[buf][bb * 36 + r * 12 + wg2 * 2 + 2]);
                fr[r][0] = u.x; fr[r][1] = u.y; fr[r][2] = v.x; fr[r][3] = v.y;
            }
#pragma unroll
            for (int oo = 0; oo < 2; ++oo)
#pragma unroll
                for (int ww = 0; ww < 2; ++ww) {
                    float a = acc[oo][ww][j];
#pragma unroll
                    for (int kh = 0; kh < 3; ++kh)
#pragma unroll
                        for (int kw = 0; kw < 3; ++kw) {
                            float prod = wk[oo][ww][kh * 3 + kw] * fr[kh][ww + kw];
                            a = a + prod;      // no FMA, (c,kh,kw) order
                        }
                    acc[oo][ww][j] = a;
                }
        }
    };

    stage(0, 0);
    __syncthreads();
    for (int cs = 0; cs < CI_; cs += 2) {
        if (cs + 1 < CI_) stage(cs + 1, 1);   // prefetch overlaps compute
        compute_c(0);
        __syncthreads();
        if (cs + 2 < CI_) stage(cs + 2, 0);
        compute_c(1);
        __syncthreads();
    }

    // epilogue: bias, park conv values, exact f64 per-slot per-channel stats
    double s1[2] = {0.0, 0.0}, s2[2] = {0.0, 0.0};
    if (val) {
#pragma unroll
        for (int oo = 0; oo < 2; ++oo) {
            const int o = ob + oo * 4 + og;
            const int pidx = o * P_ + h * WO_ + w0;
            const float2 bi = *reinterpret_cast<const float2*>(conv_bias + pidx);
#pragma unroll
            for (int j = 0; j < 4; ++j) {
                const int b = b0 + bg * 4 + j;
                const size_t n = (size_t)b * CP_ + (size_t)pidx;
                float v0 = acc[oo][0][j] + bi.x;     // f32, same as ref
                float v1 = acc[oo][1][j] + bi.y;
                *reinterpret_cast<float2*>(outf + 3 * N_ + n) = make_float2(v0, v1);
                double d0 = (double)v0, d1 = (double)v1;
                s1[oo] += d0; s2[oo] += d0 * d0;
                s1[oo] += d1; s2[oo] += d1 * d1;
            }
        }
    }
    // deterministic reduce over the 16 lanes (stride 4) sharing og
#pragma unroll
    for (int d = 4; d < 64; d <<= 1) {
#pragma unroll
        for (int oo = 0; oo < 2; ++oo) {
            s1[oo] += __shfl_xor(s1[oo], d);
            s2[oo] += __shfl_xor(s2[oo], d);
        }
    }
    if ((tid & 60) == 0) {               // wg2==0 && bg==0: tid 0..3
        int blk = (zb * 30 + h) * 4 + wt;            // same 0..959 slots
#pragma unroll
        for (int oo = 0; oo < 2; ++oo) {
            const int o = ob + oo * 4 + og;
            part_sum  [blk * CO_ + o] = s1[oo];
            part_sumsq[blk * CO_ + o] = s2[oo];
        }
    }
}

// ---------------------------------------------------------------------------
// Kernel 2: BN finalize — deterministic f64 reduction of partials (960
// slots), then f32 mean / inv_std per channel. UNCHANGED all session.
// ---------------------------------------------------------------------------
__global__ __launch_bounds__(256) void bn_finalize(
    const double* __restrict__ part_sum, const double* __restrict__ part_sumsq,
    float* __restrict__ Mb)
{
#pragma clang fp contract(off)
    const int o = blockIdx.x;
    const int tid = threadIdx.x;
    double s1 = 0.0, s2 = 0.0;
    for (int i = tid; i < NBLK_CONV; i += 256) {
        s1 += part_sum[i * CO_ + o];
        s2 += part_sumsq[i * CO_ + o];
    }
    __shared__ double r1[256], r2[256];
    r1[tid] = s1; r2[tid] = s2;
    __syncthreads();
    for (int s = 128; s > 0; s >>= 1) {
        if (tid < s) { r1[tid] += r1[tid + s]; r2[tid] += r2[tid + s]; }
        __syncthreads();
    }
    if (tid == 0) {
        const double cnt = (double)(B_ * (size_t)P_);
        double mean = r1[0] / cnt;
        float meanf = (float)mean;
        double md = (double)meanf;
        double var = r2[0] / cnt - 2.0 * md * (r1[0] / cnt) + md * md;
        float varf = (float)var;
        float invf = 1.0f / sqrtf(varf + 1e-5f);
        Mb[o]       = meanf;
        Mb[CO_ + o] = invf;
    }
}

// ---------------------------------------------------------------------------
// Kernel 3: fused recurrent-bmm + LIF. R15 VERBATIM (best measured lif:
// FETCH 84MB = algorithmic minimum). 2 batches per barrier round, 4 spike
// tiles (16 KB), register prefetch, lgkmcnt(0)-only barrier; 1024 thr =
// 32 i x 32 p (128B p-runs; narrower p inflates FETCH -- R9/R20);
// XCD-grouped grid 512 (pt8 = D&7).
// ---------------------------------------------------------------------------
__global__ __launch_bounds__(1024) void lif_rec_kernel(
    float* __restrict__ outf, const float* __restrict__ local_rec,
    const float* __restrict__ tau_m, const float* __restrict__ tau_adp,
    const float* __restrict__ tau_a, const float* __restrict__ Mb,
    const float* __restrict__ gamma, const float* __restrict__ beta,
    const float* __restrict__ fb, const float* __restrict__ soma_t,
    const float* __restrict__ spk_t, const float* __restrict__ a_curr,
    const float* __restrict__ b_t)
{
#pragma clang fp contract(off)
    const int D    = blockIdx.x;
    const int pt8  = D & 7;
    const int rest = D >> 3;
    const int by   = rest & 15;
    const int ptq  = rest >> 4;          // 0..3
    const int pt   = ptq * 8 + pt8;      // 0..31
    if (pt >= 29) return;                // 29 p-tiles cover P_=900

    const int tid = threadIdx.x;
    const int pp  = tid & 31;
    const int i   = tid >> 5;            // channel 0..31
    const int p   = pt * 32 + pp;
    const bool pv = (p < P_);
    const int b0  = by * 8;

    float L[32];
    float meanf = 0.f, invf = 0.f, gm = 0.f, be = 0.f;
    float al = 0.f, rh = 0.f, et = 0.f;
    int rem = 0;
    if (pv) {
        const float4* lp = reinterpret_cast<const float4*>(local_rec + (size_t)p * (CO_ * CO_) + i * CO_);
#pragma unroll
        for (int q = 0; q < 8; ++q) {
            float4 v = lp[q];
            L[4 * q] = v.x; L[4 * q + 1] = v.y; L[4 * q + 2] = v.z; L[4 * q + 3] = v.w;
        }
        rem = i * P_ + p;
        meanf = Mb[i]; invf = Mb[CO_ + i];
        gm = gamma[i]; be = beta[i];
        // identical f32 ops to the original tau table: f32 divide then f32 exp
        al = expf(-0.5f / tau_m[rem]);
        rh = expf(-0.5f / tau_adp[rem]);
        et = expf(-0.5f / tau_a[rem]);
    }
    const float omr = 1.0f - rh;

    __shared__ float sp[4][CO_][32];     // 16 KB: two double-buffered tile PAIRS

    // prologue: operands for batches b0, b0+1
    size_t n = (size_t)b0 * CP_ + (size_t)rem;
    float sk0 = 0.f, cv0 = 0.f, bt0 = 0.f, ac0 = 0.f, fb0 = 0.f, so0 = 0.f;
    float sk1 = 0.f, cv1 = 0.f, bt1 = 0.f, ac1 = 0.f, fb1 = 0.f, so1 = 0.f;
    if (pv) {
        sk0 = spk_t[n];       cv0 = outf[3 * N_ + n];       bt0 = b_t[n];
        ac0 = a_curr[n];      fb0 = fb[n];                  so0 = soma_t[n];
        const size_t n1 = n + (size_t)CP_;
        sk1 = spk_t[n1];      cv1 = outf[3 * N_ + n1];      bt1 = b_t[n1];
        ac1 = a_curr[n1];     fb1 = fb[n1];                 so1 = soma_t[n1];
    }

#pragma unroll
    for (int r = 0; r < 4; ++r) {
        const int t0 = (r & 1) * 2;      // literal after unroll
        if (pv) {
            sp[t0][i][pp]     = sk0;
            sp[t0 + 1][i][pp] = sk1;
        }
        // prefetch operands for batches 2r+2, 2r+3 BEFORE the barrier
        // (vmcnt ops stay in flight: the raw barrier drains lgkmcnt only)
        float sk0n = 0.f, cv0n = 0.f, bt0n = 0.f, ac0n = 0.f, fb0n = 0.f, so0n = 0.f;
        float sk1n = 0.f, cv1n = 0.f, bt1n = 0.f, ac1n = 0.f, fb1n = 0.f, so1n = 0.f;
        if (r < 3 && pv) {
            const size_t n2 = n + (size_t)(2 * CP_);
            const size_t n3 = n + (size_t)(3 * CP_);
            sk0n = spk_t[n2];  cv0n = outf[3 * N_ + n2];  bt0n = b_t[n2];
            ac0n = a_curr[n2]; fb0n = fb[n2];             so0n = soma_t[n2];
            sk1n = spk_t[n3];  cv1n = outf[3 * N_ + n3];  bt1n = b_t[n3];
            ac1n = a_curr[n3]; fb1n = fb[n3];             so1n = soma_t[n3];
        }
        asm volatile("s_waitcnt lgkmcnt(0)\n\ts_barrier" ::: "memory");
        if (pv) {
            // ---- batch 2r ----
            {
                float rec = 0.f;
#pragma unroll
                for (int j = 0; j < CO_; ++j) {
                    float prod = L[j] * sp[t0][j][pp];
                    rec = rec + prod;
                }
                float t  = cv0 - meanf;
                float x  = t * invf;
                float xg = x * gm;
                float cx = xg + be;
                cx = cx + rec;
                float rb  = rh * bt0;
                float os  = omr * sk0;
                float bn  = rb + os;
                float tb = 1.8f * bn;
                float th = 0.1f + tb;
                float ea = et * ac0;
                float an = ea + fb0;
                float sg = 1.0f / (1.0f + expf(-an));
                float as = al * so0;
                float s5 = sg - 0.5f;
                float u1 = as + s5;
                float u2 = u1 + cx;
                float ts = th * sk0;
                float sn = u2 - ts;
                outf[n]          = sn;
                outf[N_ + n]     = ((sn - th) > 0.0f) ? 1.f : 0.f;
                outf[2 * N_ + n] = an;
                outf[3 * N_ + n] = bn;
            }
            // ---- batch 2r+1 ----
            {
                const size_t n1 = n + (size_t)CP_;
                float rec = 0.f;
#pragma unroll
                for (int j = 0; j < CO_; ++j) {
                    float prod = L[j] * sp[t0 + 1][j][pp];
                    rec = rec + prod;
                }
                float t  = cv1 - meanf;
                float x  = t * invf;
                float xg = x * gm;
                float cx = xg + be;
                cx = cx + rec;
                float rb  = rh * bt1;
                float os  = omr * sk1;
                float bn  = rb + os;
                float tb = 1.8f * bn;
                float th = 0.1f + tb;
                float ea = et * ac1;
                float an = ea + fb1;
                float sg = 1.0f / (1.0f + expf(-an));
                float as = al * so1;
                float s5 = sg - 0.5f;
                float u1 = as + s5;
                float u2 = u1 + cx;
                float ts = th * sk1;
                float sn = u2 - ts;
                outf[n1]          = sn;
                outf[N_ + n1]     = ((sn - th) > 0.0f) ? 1.f : 0.f;
                outf[2 * N_ + n1] = an;
                outf[3 * N_ + n1] = bn;
            }
        }
        sk0 = sk0n; cv0 = cv0n; bt0 = bt0n; ac0 = ac0n; fb0 = fb0n; so0 = so0n;
        sk1 = sk1n; cv1 = cv1n; bt1 = bt1n; ac1 = ac1n; fb1 = fb1n; so1 = so1n;
        n += (size_t)(2 * CP_);
    }
}

extern "C" void kernel_launch(void* const* d_in, const int* in_sizes, int n_in,
                              void* d_out, int out_size, void* d_ws, size_t ws_size,
                              hipStream_t stream)
{
    const float* ff        = (const float*)d_in[0];
    const float* fb        = (const float*)d_in[1];
    const float* soma_t    = (const float*)d_in[2];
    const float* spk_t     = (const float*)d_in[3];
    const float* a_curr    = (const float*)d_in[4];
    const float* b_t       = (const float*)d_in[5];
    const float* weight    = (const float*)d_in[6];
    const float* conv_bias = (const float*)d_in[7];
    const float* local_rec = (const float*)d_in[8];
    const float* gamma     = (const float*)d_in[9];
    const float* beta      = (const float*)d_in[10];
    const float* tau_m     = (const float*)d_in[11];
    const float* tau_adp   = (const float*)d_in[12];
    const float* tau_a     = (const float*)d_in[13];

    // ws: f64 partials then Mb (~0.5 MB total)
    double* part_sum = (double*)d_ws;                       // NBLK_CONV*CO_
    double* part_sq  = part_sum + (size_t)NBLK_CONV * CO_;  // NBLK_CONV*CO_
    float*  Mb       = (float*)(part_sq + (size_t)NBLK_CONV * CO_);  // 64

    float* outf = (float*)d_out;

    conv_kernel<<<dim3(4096), 64, 0, stream>>>(
        ff, weight, conv_bias, outf, part_sum, part_sq);
    bn_finalize<<<dim3(CO_), 256, 0, stream>>>(part_sum, part_sq, Mb);
    lif_rec_kernel<<<dim3(512), 1024, 0, stream>>>(
        outf, local_rec, tau_m, tau_adp, tau_a, Mb, gamma, beta,
        fb, soma_t, spk_t, a_curr, b_t);
}